// Round 1
// baseline (248.048 us; speedup 1.0000x reference)
//
#include <hip/hip_runtime.h>

// ---------------------------------------------------------------------------
// Conv2DQwenRMSNorm: sum of 20 1x1 convs == x @ W^T with W = mean_l(conv_w),
// then RMSNorm * norm_w.  B=4,S=4096 -> M=16384 rows; H=1024 (N=K).
// Kernel 1: W[o,i] = (sum_l conv_w[l,o,i]) / 20, cast bf16, into d_ws (2MB).
// Kernel 2: fused bf16-MFMA GEMM (full-N blocks, 64 rows) + RMSNorm epilogue.
// ---------------------------------------------------------------------------

using bf16x8  = __attribute__((ext_vector_type(8))) short;
using f32x16  = __attribute__((ext_vector_type(16))) float;

#define NDIM 1024
#define MTILE 64
#define KT 32

__device__ __forceinline__ unsigned short f2bf(float f) {
    unsigned u = __float_as_uint(f);
    u += 0x7fffu + ((u >> 16) & 1u);          // RNE
    return (unsigned short)(u >> 16);
}

__device__ __forceinline__ void gload_lds16(const void* g, void* l) {
    __builtin_amdgcn_global_load_lds(
        (const __attribute__((address_space(1))) unsigned int*)g,
        (__attribute__((address_space(3))) unsigned int*)l, 16, 0, 0);
}

// ---- Kernel 1: reduce conv_w over L, cast to bf16 --------------------------
__global__ __launch_bounds__(256) void wprep_kernel(const float* __restrict__ cw,
                                                    unsigned short* __restrict__ W) {
    int idx = blockIdx.x * 256 + threadIdx.x;          // 0..262143, 4 elems each
    const float4* p = (const float4*)cw + idx;
    float4 s = make_float4(0.f, 0.f, 0.f, 0.f);
#pragma unroll
    for (int l = 0; l < 20; ++l) {
        float4 v = p[l * 262144];                      // stride = 1M floats
        s.x += v.x; s.y += v.y; s.z += v.z; s.w += v.w;
    }
    const float sc = 0.05f;                            // 1/L
    ushort4 o;
    o.x = f2bf(s.x * sc); o.y = f2bf(s.y * sc);
    o.z = f2bf(s.z * sc); o.w = f2bf(s.w * sc);
    ((ushort4*)W)[idx] = o;
}

// ---- Kernel 2: fused GEMM + RMSNorm ---------------------------------------
// grid 256 blocks (1/CU), 512 threads (8 waves). Each block: rows
// [64*bid, 64*bid+64) x all 1024 cols.  Wave w covers cols [128w,128w+128)
// as 2x4 tiles of 32x32 (mfma_f32_32x32x16_bf16).
// LDS B tile: [1024 rows][KT] bf16, 64B/row = 4 chunks of 16B; chunk XOR
// swizzle phys = logical ^ ((row>>1)&3) -> every b128 wave read/write is
// perfectly bank-balanced (8 words/bank).
__global__ __launch_bounds__(512, 2) void gemm_rms_kernel(
        const float* __restrict__ x, const unsigned short* __restrict__ W,
        const float* __restrict__ nw, float* __restrict__ out) {
    __shared__ unsigned short lA[2][MTILE * KT];       // 2 * 4 KB
    __shared__ unsigned short lB[2][NDIM * KT];        // 2 * 64 KB
    __shared__ float rowss[MTILE];

    const int tid  = threadIdx.x;
    const int wv   = tid >> 6;
    const int lane = tid & 63;
    const int ml   = lane & 31;
    const int h    = lane >> 5;
    const int row0 = blockIdx.x * MTILE;

    // A staging: thread t loads float4 of x (row am, k ak..ak+3), converts.
    const int am = tid >> 3;                           // 0..63
    const int ak = (tid & 7) << 2;                     // 0..28
    const float* aSrc = x + (size_t)(row0 + am) * NDIM + ak;
    const int aWoff = am * KT + ((((ak >> 3) ^ ((am >> 1) & 3)) << 3) | (ak & 7));

    // B staging: per wave 8 DMA of 1KB; lane -> (row j*16+(lane>>2), phys chunk lane&3).
    const char* bSrc[8];
    int ldsOffB[8];
#pragma unroll
    for (int j = 0; j < 8; ++j) {
        int n = wv * 128 + j * 16 + (lane >> 2);
        int c = (lane & 3) ^ ((n >> 1) & 3);           // logical chunk to fetch
        bSrc[j]    = (const char*)W + (size_t)n * (NDIM * 2) + c * 16;
        ldsOffB[j] = (wv * 128 + j * 16) * KT;
    }

    // Fragment LDS read offsets (elements). phys chunk = (ks*2+h) ^ ((row>>1)&3);
    // for all rows we touch, ((row>>1)&3) == ((ml>>1)&3).
    const int sw = (ml >> 1) & 3;
    int aRd[2][2], bRd[2][4];
#pragma unroll
    for (int ks = 0; ks < 2; ++ks) {
        int pc = ((ks * 2 + h) ^ sw) << 3;
#pragma unroll
        for (int tr = 0; tr < 2; ++tr) aRd[ks][tr] = (tr * 32 + ml) * KT + pc;
#pragma unroll
        for (int tc = 0; tc < 4; ++tc) bRd[ks][tc] = (wv * 128 + tc * 32 + ml) * KT + pc;
    }

    f32x16 acc[2][4];
#pragma unroll
    for (int tr = 0; tr < 2; ++tr)
#pragma unroll
        for (int tc = 0; tc < 4; ++tc)
#pragma unroll
            for (int r = 0; r < 16; ++r) acc[tr][tc][r] = 0.f;

    // ---- prologue: stage tile 0 ----
    {
        float4 v = *(const float4*)aSrc;
        ushort4 o; o.x = f2bf(v.x); o.y = f2bf(v.y); o.z = f2bf(v.z); o.w = f2bf(v.w);
        *(ushort4*)&lA[0][aWoff] = o;
#pragma unroll
        for (int j = 0; j < 8; ++j) gload_lds16(bSrc[j], &lB[0][ldsOffB[j]]);
    }
    __syncthreads();

    // ---- K loop, double buffered ----
    for (int step = 0; step < 32; ++step) {
        const int cur = step & 1, nxt = cur ^ 1;
        float4 apref;
        const bool more = (step + 1) < 32;
        if (more) {
            apref = *(const float4*)(aSrc + (step + 1) * KT);
#pragma unroll
            for (int j = 0; j < 8; ++j)
                gload_lds16(bSrc[j] + (size_t)(step + 1) * (KT * 2), &lB[nxt][ldsOffB[j]]);
        }
#pragma unroll
        for (int ks = 0; ks < 2; ++ks) {
            bf16x8 af[2], bf[4];
#pragma unroll
            for (int tr = 0; tr < 2; ++tr) af[tr] = *(const bf16x8*)&lA[cur][aRd[ks][tr]];
#pragma unroll
            for (int tc = 0; tc < 4; ++tc) bf[tc] = *(const bf16x8*)&lB[cur][bRd[ks][tc]];
#pragma unroll
            for (int tr = 0; tr < 2; ++tr)
#pragma unroll
                for (int tc = 0; tc < 4; ++tc)
                    acc[tr][tc] = __builtin_amdgcn_mfma_f32_32x32x16_bf16(
                        af[tr], bf[tc], acc[tr][tc], 0, 0, 0);
        }
        if (more) {
            ushort4 o; o.x = f2bf(apref.x); o.y = f2bf(apref.y);
            o.z = f2bf(apref.z); o.w = f2bf(apref.w);
            *(ushort4*)&lA[nxt][aWoff] = o;
        }
        __syncthreads();
    }

    // ---- epilogue: RMSNorm over each row (fully resident in block) ----
    if (tid < MTILE) rowss[tid] = 0.f;
    __syncthreads();

    // C/D layout (32x32): col = lane&31, row = (reg&3) + 8*(reg>>2) + 4*(lane>>5)
#pragma unroll
    for (int tr = 0; tr < 2; ++tr) {
#pragma unroll
        for (int r = 0; r < 16; ++r) {
            float v = 0.f;
#pragma unroll
            for (int tc = 0; tc < 4; ++tc) { float a = acc[tr][tc][r]; v += a * a; }
#pragma unroll
            for (int m = 1; m <= 16; m <<= 1) v += __shfl_xor(v, m, 64);
            if (ml == 0)
                atomicAdd(&rowss[tr * 32 + (r & 3) + 8 * (r >> 2) + 4 * h], v);
        }
    }
    __syncthreads();
    if (tid < MTILE) rowss[tid] = rsqrtf(rowss[tid] * (1.0f / 1024.0f) + 1e-6f);
    __syncthreads();

    float nwv[4];
#pragma unroll
    for (int tc = 0; tc < 4; ++tc) nwv[tc] = nw[wv * 128 + tc * 32 + ml];

#pragma unroll
    for (int tr = 0; tr < 2; ++tr) {
#pragma unroll
        for (int r = 0; r < 16; ++r) {
            const int m = tr * 32 + (r & 3) + 8 * (r >> 2) + 4 * h;
            const float rs = rowss[m];
            float* orow = out + (size_t)(row0 + m) * NDIM + wv * 128 + ml;
#pragma unroll
            for (int tc = 0; tc < 4; ++tc)
                orow[tc * 32] = acc[tr][tc][r] * rs * nwv[tc];
        }
    }
}

extern "C" void kernel_launch(void* const* d_in, const int* in_sizes, int n_in,
                              void* d_out, int out_size, void* d_ws, size_t ws_size,
                              hipStream_t stream) {
    const float* x  = (const float*)d_in[0];
    const float* cw = (const float*)d_in[1];
    const float* nw = (const float*)d_in[2];
    float* out = (float*)d_out;
    unsigned short* W = (unsigned short*)d_ws;   // 1024*1024 bf16 = 2 MB

    hipLaunchKernelGGL(wprep_kernel, dim3(1024), dim3(256), 0, stream, cw, W);
    hipLaunchKernelGGL(gemm_rms_kernel, dim3(256), dim3(512), 0, stream, x, W, nw, out);
}

// Round 2
// 235.926 us; speedup vs baseline: 1.0514x; 1.0514x over previous
//
#include <hip/hip_runtime.h>

// ---------------------------------------------------------------------------
// Conv2DQwenRMSNorm: sum of 20 1x1 convs == x @ W^T with W = mean_l(conv_w),
// then RMSNorm * norm_w.  B=4,S=4096 -> M=16384 rows; H=1024 (N=K).
//
// R2 design:
//  wprep: W = mean_l conv_w, bf16, stored FRAGMENT-MAJOR for mfma_32x32x16:
//         frag(ct,k16) = 1KB; slot lane=(h*32+ml) holds W[ct*32+ml][k16*16+h*8..+7].
//  gemm:  64 rows x full N=1024 per block (grid 256, 1/CU). A panel (64x1024
//         bf16 = 128KB) staged in LDS ONCE (frag-major, xor(k16&7) slot swizzle
//         -> conflict-free writes AND b128 reads). B fragments loaded straight
//         global->VGPR from L2-resident W (coalesced 1KB loads), depth-2
//         register pipeline, NO barriers in the K loop. RMSNorm fused epilogue.
// ---------------------------------------------------------------------------

using bf16x8 = __attribute__((ext_vector_type(8))) short;
using f32x16 = __attribute__((ext_vector_type(16))) float;

#define NDIM 1024
#define MTILE 64

__device__ __forceinline__ unsigned short f2bf(float f) {
    unsigned u = __float_as_uint(f);
    u += 0x7fffu + ((u >> 16) & 1u);          // RNE
    return (unsigned short)(u >> 16);
}

// ---- Kernel 1: reduce conv_w over L, cast bf16, write fragment-major -------
__global__ __launch_bounds__(256) void wprep_kernel(const float* __restrict__ cw,
                                                    unsigned short* __restrict__ Wf) {
    const int t  = blockIdx.x * 256 + threadIdx.x;   // 0..131071
    const int o  = t >> 7;                           // 0..1023 (output col)
    const int s  = t & 127;
    const int i0 = s << 3;                           // k base, 8 elems
    const float* p = cw + (size_t)o * NDIM + i0;
    float4 a = make_float4(0, 0, 0, 0), b = make_float4(0, 0, 0, 0);
#pragma unroll
    for (int l = 0; l < 20; ++l) {
        float4 v0 = *(const float4*)(p + (size_t)l * (NDIM * NDIM));
        float4 v1 = *(const float4*)(p + (size_t)l * (NDIM * NDIM) + 4);
        a.x += v0.x; a.y += v0.y; a.z += v0.z; a.w += v0.w;
        b.x += v1.x; b.y += v1.y; b.z += v1.z; b.w += v1.w;
    }
    const float sc = 0.05f;                          // 1/L
    bf16x8 o8;
    o8[0] = (short)f2bf(a.x * sc); o8[1] = (short)f2bf(a.y * sc);
    o8[2] = (short)f2bf(a.z * sc); o8[3] = (short)f2bf(a.w * sc);
    o8[4] = (short)f2bf(b.x * sc); o8[5] = (short)f2bf(b.y * sc);
    o8[6] = (short)f2bf(b.z * sc); o8[7] = (short)f2bf(b.w * sc);
    const int ct  = o >> 5, ml = o & 31;
    const int k16 = s >> 1, h = s & 1;
    // frag-major: byte addr = ((ct*64 + k16)*64 + h*32 + ml)*16
    *(bf16x8*)((char*)Wf + ((((ct << 6) + k16) << 6) + (h << 5) + ml) * 16) = o8;
}

// ---- Kernel 2: fused GEMM + RMSNorm ---------------------------------------
__global__ __launch_bounds__(512, 2) void gemm_rms_kernel(
        const float* __restrict__ x, const unsigned short* __restrict__ Wf,
        const float* __restrict__ nw, float* __restrict__ out) {
    __shared__ short lAf[MTILE * NDIM];              // 128 KB, frag-major
    __shared__ float rowss[MTILE];

    const int tid  = threadIdx.x;
    const int wv   = tid >> 6;
    const int lane = tid & 63;
    const int ml   = lane & 31;
    const int h    = lane >> 5;
    const int row0 = blockIdx.x * MTILE;

    if (tid < MTILE) rowss[tid] = 0.f;

    // ---- stage A panel: 64 rows x 1024 k, fp32->bf16, frag-major + swizzle --
    {
        const int row = tid >> 3;                    // 0..63
        const int rt  = row >> 5, rml = row & 31;
        const float* xr = x + (size_t)(row0 + row) * NDIM;
#pragma unroll
        for (int it = 0; it < 16; ++it) {
            const int k0 = ((tid & 7) << 3) + (it << 6);   // 0..1016 step 8
            float4 v0 = *(const float4*)(xr + k0);
            float4 v1 = *(const float4*)(xr + k0 + 4);
            bf16x8 c;
            c[0] = (short)f2bf(v0.x); c[1] = (short)f2bf(v0.y);
            c[2] = (short)f2bf(v0.z); c[3] = (short)f2bf(v0.w);
            c[4] = (short)f2bf(v1.x); c[5] = (short)f2bf(v1.y);
            c[6] = (short)f2bf(v1.z); c[7] = (short)f2bf(v1.w);
            const int k16 = k0 >> 4, hh = (k0 >> 3) & 1;
            const int slot = ((hh << 5) + rml) ^ (k16 & 7);
            *(bf16x8*)((char*)lAf + ((((rt << 6) + k16) << 10)) + (slot << 4)) = c;
        }
    }
    __syncthreads();

    // ---- K loop: depth-2 register pipeline, no barriers ----
    const char* bB[4];
#pragma unroll
    for (int c = 0; c < 4; ++c)
        bB[c] = (const char*)Wf + ((((wv << 2) + c) << 6) << 10) + (lane << 4);
    int lx[8];
#pragma unroll
    for (int s = 0; s < 8; ++s) lx[s] = (lane ^ s) << 4;

    f32x16 acc[2][4];
#pragma unroll
    for (int tr = 0; tr < 2; ++tr)
#pragma unroll
        for (int tc = 0; tc < 4; ++tc)
#pragma unroll
            for (int r = 0; r < 16; ++r) acc[tr][tc][r] = 0.f;

    bf16x8 af[2][2], bfr[2][4];
#pragma unroll
    for (int k = 0; k < 2; ++k) {
#pragma unroll
        for (int tr = 0; tr < 2; ++tr)
            af[k][tr] = *(const bf16x8*)((const char*)lAf + (((tr << 6) + k) << 10) + lx[k & 7]);
#pragma unroll
        for (int c = 0; c < 4; ++c)
            bfr[k][c] = *(const bf16x8*)(bB[c] + (k << 10));
    }

#pragma unroll
    for (int k16 = 0; k16 < 64; ++k16) {
        const int buf = k16 & 1;
        bf16x8 a0 = af[buf][0], a1 = af[buf][1];
        bf16x8 b0 = bfr[buf][0], b1 = bfr[buf][1], b2 = bfr[buf][2], b3 = bfr[buf][3];
        if (k16 + 2 < 64) {
            const int kn = k16 + 2;
#pragma unroll
            for (int tr = 0; tr < 2; ++tr)
                af[buf][tr] = *(const bf16x8*)((const char*)lAf + (((tr << 6) + kn) << 10) + lx[kn & 7]);
#pragma unroll
            for (int c = 0; c < 4; ++c)
                bfr[buf][c] = *(const bf16x8*)(bB[c] + (kn << 10));
        }
        acc[0][0] = __builtin_amdgcn_mfma_f32_32x32x16_bf16(a0, b0, acc[0][0], 0, 0, 0);
        acc[0][1] = __builtin_amdgcn_mfma_f32_32x32x16_bf16(a0, b1, acc[0][1], 0, 0, 0);
        acc[0][2] = __builtin_amdgcn_mfma_f32_32x32x16_bf16(a0, b2, acc[0][2], 0, 0, 0);
        acc[0][3] = __builtin_amdgcn_mfma_f32_32x32x16_bf16(a0, b3, acc[0][3], 0, 0, 0);
        acc[1][0] = __builtin_amdgcn_mfma_f32_32x32x16_bf16(a1, b0, acc[1][0], 0, 0, 0);
        acc[1][1] = __builtin_amdgcn_mfma_f32_32x32x16_bf16(a1, b1, acc[1][1], 0, 0, 0);
        acc[1][2] = __builtin_amdgcn_mfma_f32_32x32x16_bf16(a1, b2, acc[1][2], 0, 0, 0);
        acc[1][3] = __builtin_amdgcn_mfma_f32_32x32x16_bf16(a1, b3, acc[1][3], 0, 0, 0);
    }

    // ---- epilogue: fused RMSNorm (rows fully resident in block) ----
    __syncthreads();   // rowss init visible
    // C/D layout (32x32): col = lane&31, row = (r&3) + 8*(r>>2) + 4*(lane>>5)
#pragma unroll
    for (int tr = 0; tr < 2; ++tr) {
#pragma unroll
        for (int r = 0; r < 16; ++r) {
            float v = 0.f;
#pragma unroll
            for (int tc = 0; tc < 4; ++tc) { float a = acc[tr][tc][r]; v += a * a; }
#pragma unroll
            for (int m = 1; m <= 16; m <<= 1) v += __shfl_xor(v, m, 64);
            if (ml == 0)
                atomicAdd(&rowss[tr * 32 + (r & 3) + 8 * (r >> 2) + 4 * h], v);
        }
    }
    __syncthreads();
    if (tid < MTILE) rowss[tid] = rsqrtf(rowss[tid] * (1.0f / 1024.0f) + 1e-6f);
    __syncthreads();

    float nwv[4];
#pragma unroll
    for (int tc = 0; tc < 4; ++tc) nwv[tc] = nw[wv * 128 + tc * 32 + ml];

#pragma unroll
    for (int tr = 0; tr < 2; ++tr) {
#pragma unroll
        for (int r = 0; r < 16; ++r) {
            const int m = tr * 32 + (r & 3) + 8 * (r >> 2) + 4 * h;
            const float rs = rowss[m];
            float* orow = out + (size_t)(row0 + m) * NDIM + wv * 128 + ml;
#pragma unroll
            for (int tc = 0; tc < 4; ++tc)
                orow[tc * 32] = acc[tr][tc][r] * rs * nwv[tc];
        }
    }
}

extern "C" void kernel_launch(void* const* d_in, const int* in_sizes, int n_in,
                              void* d_out, int out_size, void* d_ws, size_t ws_size,
                              hipStream_t stream) {
    const float* x  = (const float*)d_in[0];
    const float* cw = (const float*)d_in[1];
    const float* nw = (const float*)d_in[2];
    float* out = (float*)d_out;
    unsigned short* Wf = (unsigned short*)d_ws;   // 2 MB fragment-major W

    hipLaunchKernelGGL(wprep_kernel, dim3(512), dim3(256), 0, stream, cw, Wf);
    hipLaunchKernelGGL(gemm_rms_kernel, dim3(256), dim3(512), 0, stream, x, Wf, nw, out);
}